// Round 11
// baseline (313.113 us; speedup 1.0000x reference)
//
#include <hip/hip_runtime.h>
#include <hip/hip_bf16.h>
#include <math.h>

// MEASUREMENT ROUND: 3 gemm variants x8 reps (idempotent) to surface their
// counters in rocprof top-5. V1 (R7 struct) feeds the real output path.
//   s[b,n] = sum_k x[b,k] * W'[k,n]  (M=256,N=160,K=9216), squash 16-groups.
#define M 256
#define N 160
#define K 9216
#define CH 32    // k-chunks
#define KC 288   // k per chunk = 36 p
#define BM 32
#define XST 104  // V1 Xl row stride (shorts), 96-k sub-stage
#define X3ST 296 // V3 Xl row stride (shorts), full 288-k tile

#define PART0_OFF 0
#define PART1_OFF ((size_t)8 * 1024 * 1024)  // bytes

using f32x4 = __attribute__((ext_vector_type(4))) float;
using bf16x8 = __attribute__((ext_vector_type(8))) short;

__device__ __forceinline__ ushort f2bf(float f) {
  return __builtin_bit_cast(ushort, __float2bfloat16(f));
}
__device__ __forceinline__ bf16x8 cvt8(const float4 a, const float4 b) {
  bf16x8 r;
  r[0] = (short)f2bf(a.x); r[1] = (short)f2bf(a.y);
  r[2] = (short)f2bf(a.z); r[3] = (short)f2bf(a.w);
  r[4] = (short)f2bf(b.x); r[5] = (short)f2bf(b.y);
  r[6] = (short)f2bf(b.z); r[7] = (short)f2bf(b.w);
  return r;
}

// ---------------- V1: R7 structure (LDS-staged, 3 sub-stages) ----------------
template <bool ATOMIC, int REPS>
__global__ __launch_bounds__(256) void gemm_v1(const float* __restrict__ x,
                                               const float* __restrict__ W,
                                               float* __restrict__ part) {
  __shared__ ushort Wl[12 * 1280];
  __shared__ __align__(16) ushort Xl[BM * XST];

  const int t = threadIdx.x;
  const int bx = blockIdx.x;
  const int mt = bx & 7;
  const int c = bx >> 3;
  const int m0 = mt * BM;
  const int k0 = c * KC;
  const int w = t >> 6;
  const int l = t & 63;
  const int lr = l & 15;
  const int lg = l >> 4;
  const int msub = w & 1;
  const int nh = w >> 1;

  int xrow[3], xkq[3];
#pragma unroll
  for (int q = 0; q < 3; ++q) {
    const int f = t + 256 * q;
    xrow[q] = f / 24;
    xkq[q] = (f - xrow[q] * 24) * 4;
  }

#pragma unroll 1
  for (int rep = 0; rep < REPS; ++rep) {
    float4 wv[15], xv[3];
    auto load = [&](int s) {
      const float* wsp = W + ((size_t)c * 36 + s * 12) * 1280;
#pragma unroll
      for (int q = 0; q < 15; ++q)
        wv[q] = *(const float4*)(wsp + 4 * (size_t)(t + 256 * q));
      const float* xs = x + (size_t)m0 * K + k0 + s * 96;
#pragma unroll
      for (int q = 0; q < 3; ++q)
        xv[q] = *(const float4*)(xs + (size_t)xrow[q] * K + xkq[q]);
    };
    auto put = [&]() {
#pragma unroll
      for (int q = 0; q < 15; ++q) {
        const int f4 = t + 256 * q;
        ushort4 h = {f2bf(wv[q].x), f2bf(wv[q].y), f2bf(wv[q].z),
                     f2bf(wv[q].w)};
        *(ushort4*)&Wl[4 * f4] = h;
      }
#pragma unroll
      for (int q = 0; q < 3; ++q) {
        ushort4 h = {f2bf(xv[q].x), f2bf(xv[q].y), f2bf(xv[q].z),
                     f2bf(xv[q].w)};
        *(ushort4*)&Xl[xrow[q] * XST + xkq[q]] = h;
      }
    };
    f32x4 acc[5];
#pragma unroll
    for (int nt = 0; nt < 5; ++nt) acc[nt] = {0.f, 0.f, 0.f, 0.f};
    auto comp = [&]() {
#pragma unroll
      for (int ks = 0; ks < 3; ++ks) {
        const bf16x8 a =
            *(const bf16x8*)&Xl[(msub * 16 + lr) * XST + ks * 32 + lg * 8];
#pragma unroll
        for (int nt = 0; nt < 5; ++nt) {
          const bf16x8 b =
              *(const bf16x8*)&Wl[(ks * 4 + lg) * 1280 + (nh * 5 + nt) * 128 +
                                  lr * 8];
          acc[nt] =
              __builtin_amdgcn_mfma_f32_16x16x32_bf16(a, b, acc[nt], 0, 0, 0);
        }
      }
    };
    load(0); put();
    __syncthreads();
    load(1); comp();
    __syncthreads();
    put();
    __syncthreads();
    load(2); comp();
    __syncthreads();
    put();
    __syncthreads();
    comp();

    if (ATOMIC) {
#pragma unroll
      for (int nt = 0; nt < 5; ++nt)
#pragma unroll
        for (int r = 0; r < 4; ++r) {
          const int row = m0 + msub * 16 + lg * 4 + r;
          atomicAdd(&part[(size_t)row * N + (nh * 5 + nt) * 16 + lr],
                    acc[nt][r]);
        }
    } else {
      float* dst = part + (size_t)c * (M * N);
#pragma unroll
      for (int nt = 0; nt < 5; ++nt)
#pragma unroll
        for (int r = 0; r < 4; ++r) {
          const int row = m0 + msub * 16 + lg * 4 + r;
          dst[(size_t)row * N + (nh * 5 + nt) * 16 + lr] = acc[nt][r];
        }
    }
    if (REPS > 1) __syncthreads();
    asm volatile("" ::: "memory");
  }
}

// ---------------- V2: zero-LDS, fully direct loads ----------------
template <int REPS>
__global__ __launch_bounds__(256) void gemm_v2(const float* __restrict__ x,
                                               const float* __restrict__ W,
                                               float* __restrict__ part) {
  const int t = threadIdx.x;
  const int bx = blockIdx.x;
  const int mt = bx & 7;
  const int c = bx >> 3;
  const int m0 = mt * BM;
  const int k0 = c * KC;
  const int w = t >> 6;
  const int l = t & 63;
  const int lr = l & 15;
  const int lg = l >> 4;
  const int msub = w & 1;
  const int nh = w >> 1;

  const float* xr = x + (size_t)(m0 + msub * 16 + lr) * K + k0 + lg * 8;
  const float* wb = W + ((size_t)c * 36 + lg) * 1280 + lr * 8;

#pragma unroll 1
  for (int rep = 0; rep < REPS; ++rep) {
    f32x4 acc[5];
#pragma unroll
    for (int nt = 0; nt < 5; ++nt) acc[nt] = {0.f, 0.f, 0.f, 0.f};
#pragma unroll 3
    for (int ks = 0; ks < 9; ++ks) {
      const float4 a0 = *(const float4*)(xr + ks * 32);
      const float4 a1 = *(const float4*)(xr + ks * 32 + 4);
      const bf16x8 af = cvt8(a0, a1);
#pragma unroll
      for (int nt = 0; nt < 5; ++nt) {
        const float* bp = wb + (size_t)ks * 4 * 1280 + (nh * 5 + nt) * 128;
        const bf16x8 bf =
            cvt8(*(const float4*)bp, *(const float4*)(bp + 4));
        acc[nt] =
            __builtin_amdgcn_mfma_f32_16x16x32_bf16(af, bf, acc[nt], 0, 0, 0);
      }
    }
    float* dst = part + (size_t)c * (M * N);
#pragma unroll
    for (int nt = 0; nt < 5; ++nt)
#pragma unroll
      for (int r = 0; r < 4; ++r) {
        const int row = m0 + msub * 16 + lg * 4 + r;
        dst[(size_t)row * N + (nh * 5 + nt) * 16 + lr] = acc[nt][r];
      }
    asm volatile("" ::: "memory");
  }
}

// ---------------- V3: X in LDS (full 288-k), W direct ----------------
template <int REPS>
__global__ __launch_bounds__(256) void gemm_v3(const float* __restrict__ x,
                                               const float* __restrict__ W,
                                               float* __restrict__ part) {
  __shared__ __align__(16) ushort Xl[BM * X3ST];
  const int t = threadIdx.x;
  const int bx = blockIdx.x;
  const int mt = bx & 7;
  const int c = bx >> 3;
  const int m0 = mt * BM;
  const int k0 = c * KC;
  const int w = t >> 6;
  const int l = t & 63;
  const int lr = l & 15;
  const int lg = l >> 4;
  const int msub = w & 1;
  const int nh = w >> 1;

  const float* wb = W + ((size_t)c * 36 + lg) * 1280 + lr * 8;

#pragma unroll 1
  for (int rep = 0; rep < REPS; ++rep) {
    {
      const float* xs = x + (size_t)m0 * K + k0;
#pragma unroll
      for (int q = 0; q < 9; ++q) {
        const int f = t + 256 * q;  // f4 idx < 2304
        const int row = f / 72;
        const int c4 = f - row * 72;
        const float4 v = *(const float4*)(xs + (size_t)row * K + c4 * 4);
        ushort4 h = {f2bf(v.x), f2bf(v.y), f2bf(v.z), f2bf(v.w)};
        *(ushort4*)&Xl[row * X3ST + c4 * 4] = h;
      }
    }
    __syncthreads();
    f32x4 acc[5];
#pragma unroll
    for (int nt = 0; nt < 5; ++nt) acc[nt] = {0.f, 0.f, 0.f, 0.f};
#pragma unroll 3
    for (int ks = 0; ks < 9; ++ks) {
      const bf16x8 a =
          *(const bf16x8*)&Xl[(msub * 16 + lr) * X3ST + ks * 32 + lg * 8];
#pragma unroll
      for (int nt = 0; nt < 5; ++nt) {
        const float* bp = wb + (size_t)ks * 4 * 1280 + (nh * 5 + nt) * 128;
        const bf16x8 bf =
            cvt8(*(const float4*)bp, *(const float4*)(bp + 4));
        acc[nt] =
            __builtin_amdgcn_mfma_f32_16x16x32_bf16(a, bf, acc[nt], 0, 0, 0);
      }
    }
    float* dst = part + (size_t)c * (M * N);
#pragma unroll
    for (int nt = 0; nt < 5; ++nt)
#pragma unroll
      for (int r = 0; r < 4; ++r) {
        const int row = m0 + msub * 16 + lg * 4 + r;
        dst[(size_t)row * N + (nh * 5 + nt) * 16 + lr] = acc[nt][r];
      }
    __syncthreads();
    asm volatile("" ::: "memory");
  }
}

// Reduce 32 chunks + squash. grid = 160, 256 thr.
__global__ __launch_bounds__(256) void reduce_squash4(
    const float* __restrict__ part, float* __restrict__ out) {
  __shared__ f32x4 red[256];
  const int t = threadIdx.x;
  const int o4 = t & 63;
  const int slice = t >> 6;
  const f32x4* p4 = (const f32x4*)part;
  const int base4 = blockIdx.x * 64;
  f32x4 sum = {0.f, 0.f, 0.f, 0.f};
#pragma unroll
  for (int cc = 0; cc < 8; ++cc) {
    const int c = slice * 8 + cc;
    sum += p4[(size_t)c * (M * N / 4) + base4 + o4];
  }
  red[t] = sum;
  __syncthreads();
  if (t < 64) {
    const f32x4 s = red[t] + red[t + 64] + red[t + 128] + red[t + 192];
    float n2 = s[0] * s[0] + s[1] * s[1] + s[2] * s[2] + s[3] * s[3];
    n2 += __shfl_xor(n2, 1);
    n2 += __shfl_xor(n2, 2);
    const float sc = n2 / (1.0f + n2) / sqrtf(n2 + 1e-9f);
    f32x4 o = {s[0] * sc, s[1] * sc, s[2] * sc, s[3] * sc};
    ((f32x4*)out)[base4 + t] = o;
  }
}

__global__ __launch_bounds__(256) void squash_k(float* __restrict__ out) {
  const int e = blockIdx.x * 256 + threadIdx.x;
  const float s = out[e];
  float s2 = s * s;
  s2 += __shfl_xor(s2, 1);
  s2 += __shfl_xor(s2, 2);
  s2 += __shfl_xor(s2, 4);
  s2 += __shfl_xor(s2, 8);
  out[e] = s * s2 / (1.0f + s2) / sqrtf(s2 + 1e-9f);
}

extern "C" void kernel_launch(void* const* d_in, const int* in_sizes, int n_in,
                              void* d_out, int out_size, void* d_ws,
                              size_t ws_size, hipStream_t stream) {
  const float* x = (const float*)d_in[0];  // [256,1152,8,1]
  const float* W = (const float*)d_in[1];  // [1152,10,16,8]
  float* out = (float*)d_out;              // [256,10,16,1] = 40960 f32

  const size_t need = PART1_OFF + (size_t)CH * M * N * sizeof(float);
  if (ws_size >= need) {
    float* part0 = (float*)d_ws;
    float* part1 = (float*)((char*)d_ws + PART1_OFF);
    gemm_v1<false, 8><<<256, 256, 0, stream>>>(x, W, part0);  // real + probe
    gemm_v2<8><<<256, 256, 0, stream>>>(x, W, part1);         // probe
    gemm_v3<8><<<256, 256, 0, stream>>>(x, W, part1);         // probe
    reduce_squash4<<<(M * N) / 256, 256, 0, stream>>>(part0, out);
  } else {
    hipMemsetAsync(out, 0, (size_t)M * N * sizeof(float), stream);
    gemm_v1<true, 1><<<256, 256, 0, stream>>>(x, W, out);
    squash_k<<<(M * N) / 256, 256, 0, stream>>>(out);
  }
}

// Round 12
// 18.904 us; speedup vs baseline: 16.5633x; 16.5633x over previous
//
#include <hip/hip_runtime.h>
#include <hip/hip_bf16.h>
#include <math.h>

// Reference collapses (softmax over size-1 axis == 1) to:
//   s[b,n] = sum_k x[b,k] * W'[k,n]   (M=256, N=160, K=9216)
//   W'[p*8+j][d*16+i] = W[p][d][i][j]; then squash over 16-groups of n.
// bf16 MFMA path (threshold 1.5e-2 >> bf16 error ~4e-3).
// R11: 512-thr blocks, 2 blocks/CU, 16 waves/CU -> memory concurrency.
#define M 256
#define N 160
#define K 9216
#define CH 72     // k-chunks
#define KC 128    // k per chunk = 16 p
#define BM 64
#define WPS 1288  // Wl per-p stride (shorts): 1280 + 8 pad (lg bank spread)
#define XSTR 136  // Xl row stride (shorts): 128 + 8 pad

using f32x4 = __attribute__((ext_vector_type(4))) float;
using bf16x8 = __attribute__((ext_vector_type(8))) short;

__device__ __forceinline__ ushort f2bf(float f) {
  return __builtin_bit_cast(ushort, __float2bfloat16(f));
}

// grid = 4 m-tiles * 72 chunks = 288 blocks, 512 thr (8 waves).
// LDS 58.6 KB -> 2 blocks/CU. Wave w: msub=w&3 (16 rows), nh=w>>2 (5 d's).
template <bool ATOMIC>
__global__ __launch_bounds__(512) void gemm_mfma(const float* __restrict__ x,
                                                 const float* __restrict__ W,
                                                 float* __restrict__ part) {
  __shared__ __align__(16) ushort Wl[16 * WPS];  // 41.2 KB, natural order
  __shared__ __align__(16) ushort Xl[BM * XSTR]; // 17.4 KB

  const int t = threadIdx.x;
  const int bx = blockIdx.x;
  const int mt = bx & 3;
  const int c = bx >> 2;  // 0..71
  const int m0 = mt * BM;
  const int k0 = c * KC;

  const int w = t >> 6;
  const int l = t & 63;
  const int lr = l & 15;
  const int lg = l >> 4;
  const int msub = w & 3;   // 16-row sub-tile
  const int nh = w >> 2;    // d-half: nt base = nh*5

  // ---- burst-load: 10 W f4 + 4 X f4 per thread ----
  float4 wv[10], xv[4];
  {
    const float* wsp = W + (size_t)c * 16 * 1280;
#pragma unroll
    for (int q = 0; q < 10; ++q)
      wv[q] = *(const float4*)(wsp + 4 * (size_t)(t + 512 * q));
    const float* xs = x + (size_t)m0 * K + k0;
#pragma unroll
    for (int q = 0; q < 4; ++q) {
      const int f = t + 512 * q;      // f4 idx < 2048
      const int row = f >> 5;         // 32 f4 per 128-k row
      const int k4 = f & 31;
      xv[q] = *(const float4*)(xs + (size_t)row * K + k4 * 4);
    }
  }
  // ---- convert + LDS write ----
  {
#pragma unroll
    for (int q = 0; q < 10; ++q) {
      const int f = t + 512 * q;      // f4 idx < 5120
      const int pl = f / 320;         // p-local 0..15
      const int r4 = f - pl * 320;
      ushort4 h = {f2bf(wv[q].x), f2bf(wv[q].y), f2bf(wv[q].z), f2bf(wv[q].w)};
      *(ushort4*)&Wl[pl * WPS + r4 * 4] = h;
    }
#pragma unroll
    for (int q = 0; q < 4; ++q) {
      const int f = t + 512 * q;
      const int row = f >> 5;
      const int k4 = f & 31;
      ushort4 h = {f2bf(xv[q].x), f2bf(xv[q].y), f2bf(xv[q].z), f2bf(xv[q].w)};
      *(ushort4*)&Xl[row * XSTR + k4 * 4] = h;
    }
  }
  __syncthreads();

  // ---- MFMA: 4 k-steps x 5 n-tiles per wave ----
  f32x4 acc[5];
#pragma unroll
  for (int nt = 0; nt < 5; ++nt) acc[nt] = {0.f, 0.f, 0.f, 0.f};

#pragma unroll
  for (int ks = 0; ks < 4; ++ks) {
    const bf16x8 a =
        *(const bf16x8*)&Xl[(msub * 16 + lr) * XSTR + ks * 32 + lg * 8];
#pragma unroll
    for (int nt = 0; nt < 5; ++nt) {
      // B[k=(ks*4+lg)*8+j][n=(nh*5+nt)*16+lr] = W[p0+ks*4+lg][d][i=lr][j]
      const bf16x8 b =
          *(const bf16x8*)&Wl[(ks * 4 + lg) * WPS + (nh * 5 + nt) * 128 +
                              lr * 8];
      acc[nt] = __builtin_amdgcn_mfma_f32_16x16x32_bf16(a, b, acc[nt], 0, 0, 0);
    }
  }

  // ---- store: C row = (lane>>4)*4 + reg, col = lane&15 (verified) ----
  if (ATOMIC) {
#pragma unroll
    for (int nt = 0; nt < 5; ++nt)
#pragma unroll
      for (int r = 0; r < 4; ++r) {
        const int row = m0 + msub * 16 + lg * 4 + r;
        atomicAdd(&part[(size_t)row * N + (nh * 5 + nt) * 16 + lr],
                  acc[nt][r]);
      }
  } else {
    float* dst = part + (size_t)c * (M * N);
#pragma unroll
    for (int nt = 0; nt < 5; ++nt)
#pragma unroll
      for (int r = 0; r < 4; ++r) {
        const int row = m0 + msub * 16 + lg * 4 + r;
        dst[(size_t)row * N + (nh * 5 + nt) * 16 + lr] = acc[nt][r];
      }
  }
}

// Vectorized reduce (72 chunks) + squash. grid = 160 blocks, 256 thr.
__global__ __launch_bounds__(256) void reduce_squash4(
    const float* __restrict__ part, float* __restrict__ out) {
  __shared__ f32x4 red[256];
  const int t = threadIdx.x;
  const int o4 = t & 63;
  const int slice = t >> 6;  // 0..3, 18 chunks each
  const f32x4* p4 = (const f32x4*)part;
  const int base4 = blockIdx.x * 64;

  f32x4 sum = {0.f, 0.f, 0.f, 0.f};
#pragma unroll 6
  for (int cc = 0; cc < 18; ++cc) {
    const int c = slice * 18 + cc;
    sum += p4[(size_t)c * (M * N / 4) + base4 + o4];
  }
  red[t] = sum;
  __syncthreads();
  if (t < 64) {
    const f32x4 s = red[t] + red[t + 64] + red[t + 128] + red[t + 192];
    float n2 = s[0] * s[0] + s[1] * s[1] + s[2] * s[2] + s[3] * s[3];
    n2 += __shfl_xor(n2, 1);  // quad = one 16-elem group
    n2 += __shfl_xor(n2, 2);
    const float sc = n2 / (1.0f + n2) / sqrtf(n2 + 1e-9f);
    f32x4 o = {s[0] * sc, s[1] * sc, s[2] * sc, s[3] * sc};
    ((f32x4*)out)[base4 + t] = o;
  }
}

__global__ __launch_bounds__(256) void squash_k(float* __restrict__ out) {
  const int e = blockIdx.x * 256 + threadIdx.x;
  const float s = out[e];
  float s2 = s * s;
  s2 += __shfl_xor(s2, 1);
  s2 += __shfl_xor(s2, 2);
  s2 += __shfl_xor(s2, 4);
  s2 += __shfl_xor(s2, 8);
  out[e] = s * s2 / (1.0f + s2) / sqrtf(s2 + 1e-9f);
}

extern "C" void kernel_launch(void* const* d_in, const int* in_sizes, int n_in,
                              void* d_out, int out_size, void* d_ws,
                              size_t ws_size, hipStream_t stream) {
  const float* x = (const float*)d_in[0];  // [256,1152,8,1]
  const float* W = (const float*)d_in[1];  // [1152,10,16,8]
  float* out = (float*)d_out;              // [256,10,16,1] = 40960 f32

  const size_t need = (size_t)CH * M * N * sizeof(float);  // 11.8 MB
  if (ws_size >= need) {
    gemm_mfma<false><<<4 * CH, 512, 0, stream>>>(x, W, (float*)d_ws);
    reduce_squash4<<<(M * N) / 256, 256, 0, stream>>>((const float*)d_ws, out);
  } else {
    hipMemsetAsync(out, 0, (size_t)M * N * sizeof(float), stream);
    gemm_mfma<true><<<4 * CH, 512, 0, stream>>>(x, W, out);
    squash_k<<<(M * N) / 256, 256, 0, stream>>>(out);
  }
}